// Round 1
// baseline (309.838 us; speedup 1.0000x reference)
//
#include <hip/hip_runtime.h>
#include <math.h>

namespace {

constexpr int Bc = 32, Nc = 8192, Dc = 128, Kc = 64;
constexpr int Pc = 32;                // blocks per batch in kernel 1
constexpr int ROWS = Nc / Pc;         // 256 rows per block
constexpr int ITERS = ROWS / 4;       // 64 iterations of 4 rows

// XOR permutation on float4-chunk index within a 128-float row:
// spreads the 16B slots so strided readers hit distinct bank phases.
__device__ __forceinline__ int permc(int c) { return c ^ ((c >> 3) & 1); }

// ---------------------------------------------------------------------------
// Kernel 1: fused normalize -> logits -> softmax -> a^T x accumulation.
// Each block owns (batch b, row slice p): 256 rows, acc[K][D] in registers
// (32 floats/thread), written as per-block partials (or atomics fallback).
// ---------------------------------------------------------------------------
template <bool PARTIALS>
__global__ __launch_bounds__(256) void nv_k1(
    const float* __restrict__ x, const float* __restrict__ conv_w,
    const float* __restrict__ conv_b, float* __restrict__ acc_out,
    float* __restrict__ asum_out) {
  __shared__ __align__(16) float xS[4][128];     // raw x rows, chunk-permuted
  __shared__ __align__(16) float logitS[4][68];  // raw dot products
  __shared__ __align__(16) float aS[4][68];      // a * invn
  __shared__ float invnS[4];
  __shared__ float asumS[4][64];

  const int tid = threadIdx.x;
  const int w = tid >> 6;   // wave 0..3
  const int l = tid & 63;   // lane
  const int b = blockIdx.x / Pc;
  const int p = blockIdx.x % Pc;

  // phase-2 mapping: lane = 4*k_local + dg  (dg = which d-quarter)
  const int dg = l & 3;
  const int k2 = (w << 4) + (l >> 2);  // 0..63

  // conv_w[k2][dg*32 .. dg*32+31] held in registers (8 x float4)
  float4 cwv[8];
  {
    const float4* cw4 =
        reinterpret_cast<const float4*>(conv_w + (size_t)k2 * Dc + dg * 32);
#pragma unroll
    for (int m = 0; m < 8; ++m) cwv[m] = cw4[m];
  }
  const float breg = conv_b[l];  // softmax: lane l <-> cluster l

  // phase-3 mapping: thread owns k in [4kt,4kt+4), d in [8dt,8dt+8)
  const int kt = tid >> 4;  // 0..15
  const int dt = tid & 15;  // 0..15

  float acc[4][8];
#pragma unroll
  for (int i = 0; i < 4; ++i)
#pragma unroll
    for (int j = 0; j < 8; ++j) acc[i][j] = 0.f;
  float asum_reg = 0.f;

  const float* xb = x + (size_t)b * Nc * Dc;
  const int r0 = p * ROWS;

  // software prefetch: wave w loads row (group + w), lane l -> floats 2l,2l+1
  float2 cur =
      *reinterpret_cast<const float2*>(xb + (size_t)(r0 + w) * Dc + 2 * l);

  for (int it = 0; it < ITERS; ++it) {
    // ---- phase 1: row sumsq (wave reduce) + stage raw x into LDS ----
    float ss = cur.x * cur.x + cur.y * cur.y;
#pragma unroll
    for (int o = 1; o < 64; o <<= 1) ss += __shfl_xor(ss, o);
    const float invn = 1.0f / fmaxf(sqrtf(ss), 1e-12f);
    {
      const int c = l >> 1;  // float4 chunk 0..31
      float* dst = &xS[w][0] + (permc(c) << 2) + ((l & 1) << 1);
      dst[0] = cur.x;
      dst[1] = cur.y;
    }
    if (l == 0) invnS[w] = invn;
    __syncthreads();

    // prefetch next 4-row group (hides HBM latency under phases 2-3)
    float2 nxt = make_float2(0.f, 0.f);
    if (it + 1 < ITERS)
      nxt = *reinterpret_cast<const float2*>(
          xb + (size_t)(r0 + (it + 1) * 4 + w) * Dc + 2 * l);

    // ---- phase 2: raw dots p_r = x_r . conv_w[k2] over this thread's 32 d ----
    float pr0 = 0.f, pr1 = 0.f, pr2 = 0.f, pr3 = 0.f;
#pragma unroll
    for (int m = 0; m < 8; ++m) {
      const int cp = ((dg << 3) + m) ^ (dg & 1);  // permc for c = dg*8+m
      const float4 cw = cwv[m];
      {
        const float4 xv =
            *reinterpret_cast<const float4*>(&xS[0][0] + (cp << 2));
        pr0 = fmaf(xv.x, cw.x,
                   fmaf(xv.y, cw.y, fmaf(xv.z, cw.z, fmaf(xv.w, cw.w, pr0))));
      }
      {
        const float4 xv =
            *reinterpret_cast<const float4*>(&xS[1][0] + (cp << 2));
        pr1 = fmaf(xv.x, cw.x,
                   fmaf(xv.y, cw.y, fmaf(xv.z, cw.z, fmaf(xv.w, cw.w, pr1))));
      }
      {
        const float4 xv =
            *reinterpret_cast<const float4*>(&xS[2][0] + (cp << 2));
        pr2 = fmaf(xv.x, cw.x,
                   fmaf(xv.y, cw.y, fmaf(xv.z, cw.z, fmaf(xv.w, cw.w, pr2))));
      }
      {
        const float4 xv =
            *reinterpret_cast<const float4*>(&xS[3][0] + (cp << 2));
        pr3 = fmaf(xv.x, cw.x,
                   fmaf(xv.y, cw.y, fmaf(xv.z, cw.z, fmaf(xv.w, cw.w, pr3))));
      }
    }
    // reduce the 4 d-quarters (lanes 4k..4k+3)
    pr0 += __shfl_xor(pr0, 1); pr0 += __shfl_xor(pr0, 2);
    pr1 += __shfl_xor(pr1, 1); pr1 += __shfl_xor(pr1, 2);
    pr2 += __shfl_xor(pr2, 1); pr2 += __shfl_xor(pr2, 2);
    pr3 += __shfl_xor(pr3, 1); pr3 += __shfl_xor(pr3, 2);
    // thread (k2,dg) writes row dg's raw logit (cndmask chain, no dyn reg idx)
    const float myp = (dg == 0) ? pr0 : (dg == 1) ? pr1 : (dg == 2) ? pr2 : pr3;
    logitS[dg][k2] = myp;
    __syncthreads();

    // ---- softmax: wave w handles row (it*4 + w); lane l = cluster k ----
    {
      const float invw = invnS[w];
      const float lg = logitS[w][l] * invw + breg;
      float mx = lg;
#pragma unroll
      for (int o = 1; o < 64; o <<= 1) mx = fmaxf(mx, __shfl_xor(mx, o));
      const float e = __expf(lg - mx);
      float sm = e;
#pragma unroll
      for (int o = 1; o < 64; o <<= 1) sm += __shfl_xor(sm, o);
      const float a = e / sm;
      asum_reg += a;       // unscaled a-sum for this k (rows of this wave)
      aS[w][l] = a * invw; // scaled so phase 3 can use raw x
    }
    __syncthreads();

    // ---- phase 3: rank-4 update acc[k][d] += a'[r][k] * x[r][d] ----
#pragma unroll
    for (int rr = 0; rr < 4; ++rr) {
      const float4 av =
          *reinterpret_cast<const float4*>(&aS[rr][0] + (kt << 2));
      const float4 xv0 = *reinterpret_cast<const float4*>(
          &xS[rr][0] + (permc(2 * dt) << 2));
      const float4 xv1 = *reinterpret_cast<const float4*>(
          &xS[rr][0] + (permc(2 * dt + 1) << 2));
      const float ak[4] = {av.x, av.y, av.z, av.w};
      const float xd[8] = {xv0.x, xv0.y, xv0.z, xv0.w,
                           xv1.x, xv1.y, xv1.z, xv1.w};
#pragma unroll
      for (int i = 0; i < 4; ++i)
#pragma unroll
        for (int j = 0; j < 8; ++j) acc[i][j] = fmaf(ak[i], xd[j], acc[i][j]);
    }
    __syncthreads();  // protect xS/logitS/aS before next iteration
    cur = nxt;
  }

  // combine per-wave a-sums
  asumS[w][l] = asum_reg;
  __syncthreads();

  if (PARTIALS) {
    float* accP = acc_out + (size_t)(b * Pc + p) * (Kc * Dc);
#pragma unroll
    for (int i = 0; i < 4; ++i) {
      const int k = 4 * kt + i;
      *reinterpret_cast<float4*>(accP + k * Dc + 8 * dt) =
          make_float4(acc[i][0], acc[i][1], acc[i][2], acc[i][3]);
      *reinterpret_cast<float4*>(accP + k * Dc + 8 * dt + 4) =
          make_float4(acc[i][4], acc[i][5], acc[i][6], acc[i][7]);
    }
    if (tid < 64)
      asum_out[(size_t)(b * Pc + p) * Kc + tid] =
          asumS[0][tid] + asumS[1][tid] + asumS[2][tid] + asumS[3][tid];
  } else {
    float* accA = acc_out + (size_t)b * (Kc * Dc);
#pragma unroll
    for (int i = 0; i < 4; ++i) {
      const int k = 4 * kt + i;
#pragma unroll
      for (int j = 0; j < 8; ++j)
        atomicAdd(&accA[k * Dc + 8 * dt + j], acc[i][j]);
    }
    if (tid < 64)
      atomicAdd(&asum_out[(size_t)b * Kc + tid],
                asumS[0][tid] + asumS[1][tid] + asumS[2][tid] + asumS[3][tid]);
  }
}

// ---------------------------------------------------------------------------
// Kernel 2: reduce partials, subtract centroid*asum, intra-normalize (over D),
// write out; emit per-(b, k-group) sum-of-squares for the global norm.
// Grid: Bc * 8 blocks; block (b, kg) handles clusters kg*8..kg*8+7.
// ---------------------------------------------------------------------------
template <bool PARTIALS>
__global__ __launch_bounds__(256) void nv_k2(
    const float* __restrict__ acc_in, const float* __restrict__ asum_in,
    const float* __restrict__ centroids, float* __restrict__ out,
    float* __restrict__ gssP) {
  __shared__ float asumS[8];
  __shared__ float redS[8][33];
  __shared__ float gssWv[4];
  const int tid = threadIdx.x;
  const int w = tid >> 6, l = tid & 63;
  const int b = blockIdx.x >> 3;
  const int kg = blockIdx.x & 7;

  if (PARTIALS) {
    const int kk = tid >> 5, pp = tid & 31;  // 8 x 32
    redS[kk][pp] = asum_in[(size_t)(b * Pc + pp) * Kc + kg * 8 + kk];
    __syncthreads();
    if (tid < 8) {
      float s = 0.f;
#pragma unroll
      for (int q = 0; q < 32; ++q) s += redS[tid][q];
      asumS[tid] = s;
    }
  } else {
    if (tid < 8) asumS[tid] = asum_in[(size_t)b * Kc + kg * 8 + tid];
  }
  __syncthreads();

  float gss = 0.f;
#pragma unroll
  for (int ki = 0; ki < 2; ++ki) {
    const int kloc = w + 4 * ki;  // 0..7
    const int k = kg * 8 + kloc;
    float v0 = 0.f, v1 = 0.f;
    if (PARTIALS) {
      for (int pp = 0; pp < Pc; ++pp) {
        const float2 t = *reinterpret_cast<const float2*>(
            acc_in + (size_t)(b * Pc + pp) * (Kc * Dc) + k * Dc + 2 * l);
        v0 += t.x;
        v1 += t.y;
      }
    } else {
      const float2 t = *reinterpret_cast<const float2*>(
          acc_in + (size_t)b * (Kc * Dc) + k * Dc + 2 * l);
      v0 = t.x;
      v1 = t.y;
    }
    const float as = asumS[kloc];
    const float2 c2 =
        *reinterpret_cast<const float2*>(centroids + (size_t)k * Dc + 2 * l);
    v0 -= c2.x * as;
    v1 -= c2.y * as;
    float ssk = v0 * v0 + v1 * v1;
#pragma unroll
    for (int o = 1; o < 64; o <<= 1) ssk += __shfl_xor(ssk, o);
    const float sc = 1.0f / fmaxf(sqrtf(ssk), 1e-12f);
    gss += ssk * sc * sc;  // contribution to global sumsq (post intra-norm)
    float2* o2 = reinterpret_cast<float2*>(out + (size_t)b * (Kc * Dc) +
                                           k * Dc + 2 * l);
    *o2 = make_float2(v0 * sc, v1 * sc);
  }
  if (l == 0) gssWv[w] = gss;
  __syncthreads();
  if (tid == 0) gssP[blockIdx.x] = gssWv[0] + gssWv[1] + gssWv[2] + gssWv[3];
}

// ---------------------------------------------------------------------------
// Kernel 3: global L2 normalization (scale by rsqrt of summed gss per batch).
// ---------------------------------------------------------------------------
__global__ __launch_bounds__(256) void nv_k3(float* __restrict__ out,
                                             const float* __restrict__ gssP) {
  const int bid = blockIdx.x;  // 256 blocks x 256 threads x float4 = 262144
  const int b = bid >> 3;      // 8 blocks per batch (8192 floats each)
  float g = 0.f;
#pragma unroll
  for (int i = 0; i < 8; ++i) g += gssP[b * 8 + i];
  const float gsc = 1.0f / fmaxf(sqrtf(g), 1e-12f);
  float4* o4 =
      reinterpret_cast<float4*>(out) + (size_t)bid * 256 + threadIdx.x;
  float4 v = *o4;
  v.x *= gsc;
  v.y *= gsc;
  v.z *= gsc;
  v.w *= gsc;
  *o4 = v;
}

}  // namespace

extern "C" void kernel_launch(void* const* d_in, const int* in_sizes, int n_in,
                              void* d_out, int out_size, void* d_ws,
                              size_t ws_size, hipStream_t stream) {
  const float* x = (const float*)d_in[0];
  const float* ce = (const float*)d_in[1];
  const float* cw = (const float*)d_in[2];
  const float* cb = (const float*)d_in[3];
  float* out = (float*)d_out;

  const size_t accPf = (size_t)Bc * Pc * Kc * Dc;  // 8.39M floats (33.6 MB)
  const size_t asumPf = (size_t)Bc * Pc * Kc;      // 65536 floats
  const size_t gssf = (size_t)Bc * 8;              // 256 floats
  const size_t needP = (accPf + asumPf + gssf) * sizeof(float);

  if (ws_size >= needP) {
    float* accP = (float*)d_ws;
    float* asumP = accP + accPf;
    float* gssP = asumP + asumPf;
    nv_k1<true><<<Bc * Pc, 256, 0, stream>>>(x, cw, cb, accP, asumP);
    nv_k2<true><<<Bc * 8, 256, 0, stream>>>(accP, asumP, ce, out, gssP);
    nv_k3<<<256, 256, 0, stream>>>(out, gssP);
  } else {
    // atomics fallback: acc [Bc][K*D] + asum [Bc][K] + gss [Bc*8]
    float* accA = (float*)d_ws;
    float* asumA = accA + (size_t)Bc * Kc * Dc;
    float* gssP = asumA + (size_t)Bc * Kc;
    hipMemsetAsync(d_ws, 0,
                   ((size_t)Bc * Kc * Dc + (size_t)Bc * Kc) * sizeof(float),
                   stream);
    nv_k1<false><<<Bc * Pc, 256, 0, stream>>>(x, cw, cb, accA, asumA);
    nv_k2<false><<<Bc * 8, 256, 0, stream>>>(accA, asumA, ce, out, gssP);
    nv_k3<<<256, 256, 0, stream>>>(out, gssP);
  }
}

// Round 2
// 53.654 us; speedup vs baseline: 5.7747x; 5.7747x over previous
//
#include <hip/hip_runtime.h>
#include <math.h>

namespace {

typedef float f32x4 __attribute__((ext_vector_type(4)));
typedef float f32x16 __attribute__((ext_vector_type(16)));
typedef short bf16x8 __attribute__((ext_vector_type(8)));

constexpr int Bc = 32, Nc = 8192, Dc = 128, Kc = 64;
constexpr int PB = 16;            // blocks per batch
constexpr int RPB = Nc / PB;      // 512 rows per block
constexpr int NT = 64;            // rows per iteration tile
constexpr int ITERS = RPB / NT;   // 8
constexpr int XSTR = 136;         // xS row stride in shorts (272 B, 16B-aligned)

__device__ __forceinline__ unsigned short f2bf(float f) {
  unsigned int u = __builtin_bit_cast(unsigned int, f);
  u = (u + 0x7FFFu + ((u >> 16) & 1u)) >> 16;  // RNE
  return (unsigned short)u;
}
__device__ __forceinline__ unsigned int pk(float a, float b) {
  return (unsigned int)f2bf(a) | ((unsigned int)f2bf(b) << 16);
}

// ---------------------------------------------------------------------------
// Kernel 1: per 64-row tile: L2-normalize -> bf16 LDS tile -> MFMA logits
// (W in registers) -> in-wave softmax -> swizzled a^T tile -> MFMA a^T x.
// Block = 256 threads (4 waves); wave w owns logit rows [16w,16w+16) and
// output d-columns [32w, 32w+32). acc[64][128] accumulated in AGPR fragments.
// ---------------------------------------------------------------------------
__global__ __launch_bounds__(256, 2) void nv_k1(
    const float* __restrict__ x, const float* __restrict__ conv_w,
    const float* __restrict__ conv_b, float* __restrict__ accP,
    float* __restrict__ asumP) {
  __shared__ __align__(16) short xS[NT * XSTR];  // xn tile, bf16
  __shared__ __align__(16) short aT[Kc * NT];    // a^T tile, bf16, chunk-swizzled
  __shared__ float asumS[4 * 64];

  const int tid = threadIdx.x;
  const int w = tid >> 6, l = tid & 63;
  const int bp = blockIdx.x;  // 0..511
  const int b = bp / PB, p = bp % PB;
  const float* xb = x + (size_t)b * Nc * Dc + (size_t)p * RPB * Dc;

  // --- conv_w fragments (bf16, B-operand of GEMM1) + bias, held in regs ---
  bf16x8 wf[4][4];
  float cb[4];
#pragma unroll
  for (int nt = 0; nt < 4; ++nt) {
    const int k = (l & 15) + 16 * nt;
    cb[nt] = conv_b[k];
#pragma unroll
    for (int ks = 0; ks < 4; ++ks) {
      const float* wp = conv_w + k * Dc + 8 * (l >> 4) + 32 * ks;
      const float4 w0 = *(const float4*)wp;
      const float4 w1 = *(const float4*)(wp + 4);
      union { unsigned int u[4]; bf16x8 v; } fu;
      fu.u[0] = pk(w0.x, w0.y); fu.u[1] = pk(w0.z, w0.w);
      fu.u[2] = pk(w1.x, w1.y); fu.u[3] = pk(w1.z, w1.w);
      wf[nt][ks] = fu.v;
    }
  }

  f32x16 acc2[2];
#pragma unroll
  for (int mt = 0; mt < 2; ++mt)
#pragma unroll
    for (int r = 0; r < 16; ++r) acc2[mt][r] = 0.f;
  float asum_acc[4] = {0.f, 0.f, 0.f, 0.f};

  // staging: thread owns row sr (0..63), quarter sq (32 floats, contiguous)
  const int sr = tid >> 2, sq = tid & 3;
  float4 cur[8];
  {
    const float* gp = xb + (size_t)sr * Dc + 32 * sq;
#pragma unroll
    for (int j = 0; j < 8; ++j) cur[j] = *(const float4*)(gp + 4 * j);
  }

  const int dcol = (l & 31) + 32 * w;  // this lane's output d-column (GEMM2)

  for (int it = 0; it < ITERS; ++it) {
    // ---- normalize (4-lane shfl reduce) + cvt to bf16 ----
    float ss = 0.f;
#pragma unroll
    for (int j = 0; j < 8; ++j)
      ss += cur[j].x * cur[j].x + cur[j].y * cur[j].y +
            cur[j].z * cur[j].z + cur[j].w * cur[j].w;
    ss += __shfl_xor(ss, 1);
    ss += __shfl_xor(ss, 2);
    const float invn = 1.0f / fmaxf(sqrtf(ss), 1e-12f);
    unsigned int xv[16];
#pragma unroll
    for (int j = 0; j < 8; ++j) {
      xv[2 * j] = pk(cur[j].x * invn, cur[j].y * invn);
      xv[2 * j + 1] = pk(cur[j].z * invn, cur[j].w * invn);
    }
    __syncthreads();  // previous iteration's GEMM2 done with xS/aT
    {
      short* dst = xS + sr * XSTR + 32 * sq;
#pragma unroll
      for (int j = 0; j < 4; ++j) {
        union { unsigned int u[4]; bf16x8 v; } fu;
        fu.u[0] = xv[4 * j]; fu.u[1] = xv[4 * j + 1];
        fu.u[2] = xv[4 * j + 2]; fu.u[3] = xv[4 * j + 3];
        *(bf16x8*)(dst + 8 * j) = fu.v;
      }
    }
    // prefetch next tile (in flight across GEMM phases)
    if (it + 1 < ITERS) {
      const float* gp = xb + (size_t)((it + 1) * NT + sr) * Dc + 32 * sq;
#pragma unroll
      for (int j = 0; j < 8; ++j) cur[j] = *(const float4*)(gp + 4 * j);
    }
    __syncthreads();  // xS ready

    // ---- GEMM1: logits[16 rows x 64 k] for wave w ----
    f32x4 c1[4];
#pragma unroll
    for (int nt = 0; nt < 4; ++nt) {
      c1[nt][0] = 0.f; c1[nt][1] = 0.f; c1[nt][2] = 0.f; c1[nt][3] = 0.f;
    }
#pragma unroll
    for (int ks = 0; ks < 4; ++ks) {
      const bf16x8 af =
          *(const bf16x8*)(xS + (16 * w + (l & 15)) * XSTR + 8 * (l >> 4) + 32 * ks);
#pragma unroll
      for (int nt = 0; nt < 4; ++nt)
        c1[nt] = __builtin_amdgcn_mfma_f32_16x16x32_bf16(af, wf[nt][ks],
                                                         c1[nt], 0, 0, 0);
    }

    // ---- softmax (in-lane + 16-lane-group shfl); rows n = 16w+4*(l>>4)+i ----
    float a4[4][4];
#pragma unroll
    for (int nt = 0; nt < 4; ++nt)
#pragma unroll
      for (int i = 0; i < 4; ++i) a4[nt][i] = c1[nt][i] + cb[nt];
#pragma unroll
    for (int i = 0; i < 4; ++i) {
      float mx = fmaxf(fmaxf(a4[0][i], a4[1][i]), fmaxf(a4[2][i], a4[3][i]));
      mx = fmaxf(mx, __shfl_xor(mx, 1));
      mx = fmaxf(mx, __shfl_xor(mx, 2));
      mx = fmaxf(mx, __shfl_xor(mx, 4));
      mx = fmaxf(mx, __shfl_xor(mx, 8));
      float s = 0.f;
#pragma unroll
      for (int nt = 0; nt < 4; ++nt) {
        a4[nt][i] = __expf(a4[nt][i] - mx);
        s += a4[nt][i];
      }
      s += __shfl_xor(s, 1);
      s += __shfl_xor(s, 2);
      s += __shfl_xor(s, 4);
      s += __shfl_xor(s, 8);
      const float inv = __builtin_amdgcn_rcpf(s);
#pragma unroll
      for (int nt = 0; nt < 4; ++nt) a4[nt][i] *= inv;
    }
    // ---- asum accumulate + a^T tile write (swizzled chunks) ----
#pragma unroll
    for (int nt = 0; nt < 4; ++nt) {
      float s = a4[nt][0] + a4[nt][1] + a4[nt][2] + a4[nt][3];
      s += __shfl_xor(s, 16);
      s += __shfl_xor(s, 32);
      asum_acc[nt] += s;
      const int k = (l & 15) + 16 * nt;
      const int cn = 4 * w + (l >> 4);  // n-chunk (4 rows)
      const unsigned int u0 = pk(a4[nt][0], a4[nt][1]);
      const unsigned int u1 = pk(a4[nt][2], a4[nt][3]);
      *(uint2*)(aT + k * NT + ((cn ^ (l & 15)) << 2)) = make_uint2(u0, u1);
    }
    __syncthreads();  // aT ready

    // ---- GEMM2: acc[k][d] += a^T[k][n] * xn[n][d], 32x32x16 ----
#pragma unroll
    for (int ks2 = 0; ks2 < 4; ++ks2) {
      const int n0 = 16 * ks2 + 8 * (l >> 5);
      union { unsigned int u[4]; bf16x8 v; } bu;
#pragma unroll
      for (int j = 0; j < 4; ++j) {
        const unsigned short s0 =
            *(const unsigned short*)(xS + (n0 + 2 * j) * XSTR + dcol);
        const unsigned short s1 =
            *(const unsigned short*)(xS + (n0 + 2 * j + 1) * XSTR + dcol);
        bu.u[j] = (unsigned int)s0 | ((unsigned int)s1 << 16);
      }
#pragma unroll
      for (int mt = 0; mt < 2; ++mt) {
        const int k = (l & 31) + 32 * mt;
        const int cn = n0 >> 2;
        const uint2 lo = *(const uint2*)(aT + k * NT + (((cn)     ^ (k & 15)) << 2));
        const uint2 hi = *(const uint2*)(aT + k * NT + (((cn + 1) ^ (k & 15)) << 2));
        union { unsigned int u[4]; bf16x8 v; } au;
        au.u[0] = lo.x; au.u[1] = lo.y; au.u[2] = hi.x; au.u[3] = hi.y;
        acc2[mt] = __builtin_amdgcn_mfma_f32_32x32x16_bf16(au.v, bu.v,
                                                           acc2[mt], 0, 0, 0);
      }
    }
    // next iteration's top barrier protects xS/aT from overwrite
  }

  // ---- epilogue: asum combine + partial acc write ----
#pragma unroll
  for (int nt = 0; nt < 4; ++nt)
    if (l < 16) asumS[w * 64 + nt * 16 + (l & 15)] = asum_acc[nt];
  __syncthreads();
  if (tid < 64)
    asumP[(size_t)bp * Kc + tid] =
        asumS[tid] + asumS[64 + tid] + asumS[128 + tid] + asumS[192 + tid];

  float* ap = accP + (size_t)bp * (Kc * Dc);
#pragma unroll
  for (int mt = 0; mt < 2; ++mt)
#pragma unroll
    for (int r = 0; r < 16; ++r) {
      const int k = 32 * mt + (r & 3) + 8 * (r >> 2) + 4 * (l >> 5);
      ap[k * Dc + dcol] = acc2[mt][r];
    }
}

// ---------------------------------------------------------------------------
// Kernel 2: reduce 16 partials, subtract centroid*asum, intra-normalize over D,
// write out; emit per-(b,kg) sum-of-squares for the global norm.
// ---------------------------------------------------------------------------
__global__ __launch_bounds__(256) void nv_k2(
    const float* __restrict__ accP, const float* __restrict__ asumP,
    const float* __restrict__ cent, float* __restrict__ out,
    float* __restrict__ gssP) {
  __shared__ float asumS[8];
  __shared__ float redS[8][17];
  __shared__ float gssWv[4];
  const int tid = threadIdx.x;
  const int w = tid >> 6, l = tid & 63;
  const int b = blockIdx.x >> 3;
  const int kg = blockIdx.x & 7;

  if (tid < 128)
    redS[tid >> 4][tid & 15] =
        asumP[(size_t)(b * PB + (tid & 15)) * Kc + kg * 8 + (tid >> 4)];
  __syncthreads();
  if (tid < 8) {
    float s = 0.f;
#pragma unroll
    for (int q = 0; q < 16; ++q) s += redS[tid][q];
    asumS[tid] = s;
  }
  __syncthreads();

  float gss = 0.f;
#pragma unroll
  for (int ki = 0; ki < 2; ++ki) {
    const int kloc = w + 4 * ki, k = kg * 8 + kloc;
    float v0 = 0.f, v1 = 0.f;
    for (int pp = 0; pp < PB; ++pp) {
      const float2 t = *(const float2*)(accP + (size_t)(b * PB + pp) * (Kc * Dc) +
                                        k * Dc + 2 * l);
      v0 += t.x;
      v1 += t.y;
    }
    const float as = asumS[kloc];
    const float2 c2 = *(const float2*)(cent + (size_t)k * Dc + 2 * l);
    v0 -= c2.x * as;
    v1 -= c2.y * as;
    float ssk = v0 * v0 + v1 * v1;
#pragma unroll
    for (int o = 1; o < 64; o <<= 1) ssk += __shfl_xor(ssk, o);
    const float sc = 1.0f / fmaxf(sqrtf(ssk), 1e-12f);
    gss += ssk * sc * sc;
    float2* o2 =
        reinterpret_cast<float2*>(out + (size_t)b * (Kc * Dc) + k * Dc + 2 * l);
    *o2 = make_float2(v0 * sc, v1 * sc);
  }
  if (l == 0) gssWv[w] = gss;
  __syncthreads();
  if (tid == 0) gssP[blockIdx.x] = gssWv[0] + gssWv[1] + gssWv[2] + gssWv[3];
}

// ---------------------------------------------------------------------------
// Kernel 3: global L2 normalization.
// ---------------------------------------------------------------------------
__global__ __launch_bounds__(256) void nv_k3(float* __restrict__ out,
                                             const float* __restrict__ gssP) {
  const int bid = blockIdx.x;
  const int b = bid >> 3;
  float g = 0.f;
#pragma unroll
  for (int i = 0; i < 8; ++i) g += gssP[b * 8 + i];
  const float gsc = 1.0f / fmaxf(sqrtf(g), 1e-12f);
  float4* o4 = reinterpret_cast<float4*>(out) + (size_t)bid * 256 + threadIdx.x;
  float4 v = *o4;
  v.x *= gsc;
  v.y *= gsc;
  v.z *= gsc;
  v.w *= gsc;
  *o4 = v;
}

}  // namespace

extern "C" void kernel_launch(void* const* d_in, const int* in_sizes, int n_in,
                              void* d_out, int out_size, void* d_ws,
                              size_t ws_size, hipStream_t stream) {
  const float* x = (const float*)d_in[0];
  const float* ce = (const float*)d_in[1];
  const float* cw = (const float*)d_in[2];
  const float* cb = (const float*)d_in[3];
  float* out = (float*)d_out;

  const size_t accPf = (size_t)Bc * PB * Kc * Dc;  // 4.19M floats (16.8 MB)
  const size_t asumPf = (size_t)Bc * PB * Kc;      // 32768 floats
  float* accP = (float*)d_ws;
  float* asumP = accP + accPf;
  float* gssP = asumP + asumPf;

  nv_k1<<<Bc * PB, 256, 0, stream>>>(x, cw, cb, accP, asumP);
  nv_k2<<<Bc * 8, 256, 0, stream>>>(accP, asumP, ce, out, gssP);
  nv_k3<<<256, 256, 0, stream>>>(out, gssP);
}